// Round 4
// baseline (622.981 us; speedup 1.0000x reference)
//
#include <hip/hip_runtime.h>

#define TT 4096
#define T1 4097

using f32x4 = __attribute__((ext_vector_type(4))) float;

// ---------------- batched GEMV: Y[b][j] += sum_k X[b][k] * W[k][j], all f32 --------
// block 256: ct = tid&7 (4 cols -> 32 cols/block), kt = tid>>3 (32-way k parallel)
// grid (N/32, KS); chunk = K/KS. Y pre-zeroed, atomically accumulated.
__global__ __launch_bounds__(256) void gemv_atomic(const float* __restrict__ X,
                                                   const float* __restrict__ W,
                                                   float* __restrict__ Y,
                                                   int N, int K, int chunk) {
  const int tid = threadIdx.x;
  const int ct = tid & 7;
  const int kt = tid >> 3;
  const int col0 = blockIdx.x * 32 + ct * 4;
  const int k0 = blockIdx.y * chunk;
  float acc[4][4];
#pragma unroll
  for (int c = 0; c < 4; ++c)
#pragma unroll
    for (int b = 0; b < 4; ++b) acc[c][b] = 0.f;
  const int iters = chunk >> 5;
  for (int i = 0; i < iters; ++i) {
    int k = k0 + kt + (i << 5);
    f32x4 w4 = *(const f32x4*)(W + (size_t)k * N + col0);
    float xb[4];
#pragma unroll
    for (int b = 0; b < 4; ++b) xb[b] = X[(size_t)b * K + k];
#pragma unroll
    for (int c = 0; c < 4; ++c)
#pragma unroll
      for (int b = 0; b < 4; ++b) acc[c][b] += w4[c] * xb[b];
  }
  __shared__ float red[256][16];
#pragma unroll
  for (int c = 0; c < 4; ++c)
#pragma unroll
    for (int b = 0; b < 4; ++b) red[tid][c * 4 + b] = acc[c][b];
  __syncthreads();
  for (int s = 16; s >= 1; s >>= 1) {
    if (kt < s) {
#pragma unroll
      for (int j = 0; j < 16; ++j) red[tid][j] += red[tid + 8 * s][j];
    }
    __syncthreads();
  }
  if (kt == 0) {
#pragma unroll
    for (int c = 0; c < 4; ++c)
#pragma unroll
      for (int b = 0; b < 4; ++b)
        atomicAdd(&Y[(size_t)b * N + col0 + c], red[ct][c * 4 + b]);
  }
}

// ---------------- absorb: q_abs[b][n][v] = sum_d qC[b][n][d] * W_UK[v][n][d] ------
// grid (32 n, 4 vt); block 128: one thread per v
__global__ __launch_bounds__(128) void absorb_kernel(const float* __restrict__ qC,
                                                     const float* __restrict__ W_UK,
                                                     float* __restrict__ q_abs) {
  const int n = blockIdx.x, vt = blockIdx.y;
  __shared__ float qs[4][128];
  for (int i = threadIdx.x; i < 512; i += 128)
    qs[i >> 7][i & 127] = qC[(size_t)(i >> 7) * 4096 + n * 128 + (i & 127)];
  __syncthreads();
  const int v = vt * 128 + threadIdx.x;
  const float* wp = W_UK + (size_t)v * 4096 + n * 128;
  float acc[4] = {0.f, 0.f, 0.f, 0.f};
  for (int c = 0; c < 32; ++c) {
    f32x4 w4 = *(const f32x4*)(wp + c * 4);
#pragma unroll
    for (int j = 0; j < 4; ++j)
#pragma unroll
      for (int b = 0; b < 4; ++b) acc[b] += qs[b][c * 4 + j] * w4[j];
  }
#pragma unroll
  for (int b = 0; b < 4; ++b) q_abs[((size_t)(b * 32) + n) * 512 + v] = acc[b];
}

// ---------------- cache concat-copy: f32 src[b][T*L] -> f32 dst[b][T1*L] ----------
// idx indexes vec4s; shift = log2(T*L/4); dstStride = T1*L (elements)
__global__ __launch_bounds__(256) void copy_cache(const float* __restrict__ src,
                                                  float* __restrict__ dst,
                                                  int shift, size_t dstStride) {
  size_t idx = (size_t)blockIdx.x * 256 + threadIdx.x;
  const size_t total = (size_t)4 << shift;
  for (; idx < total; idx += (size_t)gridDim.x * 256) {
    int b = (int)(idx >> shift);
    size_t rem = idx & (((size_t)1 << shift) - 1);
    f32x4 v = *(const f32x4*)(src + (idx << 2));
    *(f32x4*)(dst + (size_t)b * dstStride + (rem << 2)) = v;
  }
}

// ---------------- prefix scores ----------------------------------------------------
// grid (256 t-tiles of 16, 4 b); block 256: n = tid&31, tg = tid>>5 (2 t each)
__global__ __launch_bounds__(256) void scores_kernel(const float* __restrict__ cKV,
                                                     const float* __restrict__ kR,
                                                     const float* __restrict__ q_abs,
                                                     const float* __restrict__ qR,
                                                     float* __restrict__ scores) {
  const int b = blockIdx.y;
  const int t0 = blockIdx.x * 16;
  const int tid = threadIdx.x;
  __shared__ float ck[16][512];  // 32 KB
  for (int i = tid; i < 2048; i += 256) {
    int tl = i >> 7, vc = i & 127;
    *(f32x4*)&ck[tl][vc * 4] = *(const f32x4*)(cKV + ((size_t)b * TT + t0 + tl) * 512 + vc * 4);
  }
  __syncthreads();
  const int n = tid & 31, tg = tid >> 5;
  const float* qa = q_abs + ((size_t)(b * 32) + n) * 512;
  float acc[2] = {0.f, 0.f};
  for (int vc = 0; vc < 128; ++vc) {
    f32x4 q4 = *(const f32x4*)(qa + vc * 4);
#pragma unroll
    for (int i = 0; i < 2; ++i) {
      f32x4 c4 = *(const f32x4*)&ck[tg * 2 + i][vc * 4];
#pragma unroll
      for (int j = 0; j < 4; ++j) acc[i] += q4[j] * c4[j];
    }
  }
  const float* qrp = qR + (size_t)b * 2048 + n * 64;
  for (int rc = 0; rc < 16; ++rc) {
    f32x4 q4 = *(const f32x4*)(qrp + rc * 4);
#pragma unroll
    for (int i = 0; i < 2; ++i) {
      f32x4 k4 = *(const f32x4*)(kR + (((size_t)b * TT + t0 + tg * 2 + i) * 32 + n) * 64 + rc * 4);
#pragma unroll
      for (int j = 0; j < 4; ++j) acc[i] += q4[j] * k4[j];
    }
  }
#pragma unroll
  for (int i = 0; i < 2; ++i)
    scores[((size_t)(b * 32) + n) * T1 + t0 + tg * 2 + i] = acc[i];
}

// ---------------- softmax (adds new-token score, mask, scale) ---------------------
// grid 128 (b*32+n); block 256
__global__ __launch_bounds__(256) void softmax_kernel(float* __restrict__ scores,
                                                      const float* __restrict__ mask,
                                                      const float* __restrict__ q_abs,
                                                      const float* __restrict__ cKV_t,
                                                      const float* __restrict__ qR,
                                                      const float* __restrict__ kR_t) {
  const int b = blockIdx.x >> 5, n = blockIdx.x & 31;
  const int tid = threadIdx.x;
  float* srow = scores + ((size_t)(b * 32) + n) * T1;
  const float* qa = q_abs + ((size_t)(b * 32) + n) * 512;
  const float* ck = cKV_t + b * 512;
  float p = qa[tid] * ck[tid] + qa[tid + 256] * ck[tid + 256];
  if (tid < 64) p += qR[(size_t)b * 2048 + n * 64 + tid] * kR_t[(size_t)b * 2048 + n * 64 + tid];
  __shared__ float lds[256];
  lds[tid] = p;
  __syncthreads();
  for (int s = 128; s >= 1; s >>= 1) {
    if (tid < s) lds[tid] += lds[tid + s];
    __syncthreads();
  }
  const float sT = lds[0];
  __syncthreads();
  const float inv_scale = 0.0721687836487032f;  // 1/sqrt(192)
  const float* mrow = mask + ((size_t)(b * 32) + n) * T1;
  float lmax = -1e30f;
  for (int t = tid; t < T1; t += 256) {
    float s0 = (t < TT) ? srow[t] : sT;
    float val = s0 * inv_scale + mrow[t] * (-1e9f);
    srow[t] = val;
    lmax = fmaxf(lmax, val);
  }
  lds[tid] = lmax;
  __syncthreads();
  for (int s = 128; s >= 1; s >>= 1) {
    if (tid < s) lds[tid] = fmaxf(lds[tid], lds[tid + s]);
    __syncthreads();
  }
  const float M = lds[0];
  __syncthreads();
  float lsum = 0.f;
  for (int t = tid; t < T1; t += 256) {
    float e = expf(srow[t] - M);
    srow[t] = e;
    lsum += e;
  }
  lds[tid] = lsum;
  __syncthreads();
  for (int s = 128; s >= 1; s >>= 1) {
    if (tid < s) lds[tid] += lds[tid + s];
    __syncthreads();
  }
  const float inv = 1.0f / lds[0];
  for (int t = tid; t < T1; t += 256) srow[t] *= inv;
}

// ---------------- aggregation: agg[b][n][v] += sum_t probs*cKV (atomic over chunks)
// grid (32 chunks of 128 t, 4 b); block 256: n0 = tid&7, vg = tid>>3
__global__ __launch_bounds__(256) void agg_kernel(const float* __restrict__ cKV,
                                                  const float* __restrict__ probs,
                                                  float* __restrict__ agg) {
  const int chunk = blockIdx.x, b = blockIdx.y;
  const int tid = threadIdx.x;
  const int n0 = tid & 7, vg = tid >> 3;
  const int t0 = chunk * 128;
  __shared__ float p_lds[32 * 129];
  for (int i = tid; i < 4096; i += 256) {
    int n = i >> 7, tl = i & 127;
    p_lds[n * 129 + tl] = probs[((size_t)(b * 32) + n) * T1 + t0 + tl];
  }
  __syncthreads();
  float acc[4][16];
#pragma unroll
  for (int a = 0; a < 4; ++a)
#pragma unroll
    for (int j = 0; j < 16; ++j) acc[a][j] = 0.f;
  for (int t = 0; t < 128; ++t) {
    const float* cp = cKV + ((size_t)b * TT + t0 + t) * 512 + vg * 16;
    f32x4 c0 = *(const f32x4*)(cp);
    f32x4 c1 = *(const f32x4*)(cp + 4);
    f32x4 c2 = *(const f32x4*)(cp + 8);
    f32x4 c3 = *(const f32x4*)(cp + 12);
    float cf[16];
#pragma unroll
    for (int j = 0; j < 4; ++j) {
      cf[j] = c0[j]; cf[j + 4] = c1[j]; cf[j + 8] = c2[j]; cf[j + 12] = c3[j];
    }
#pragma unroll
    for (int a = 0; a < 4; ++a) {
      float pv = p_lds[(n0 + 8 * a) * 129 + t];
#pragma unroll
      for (int j = 0; j < 16; ++j) acc[a][j] += pv * cf[j];
    }
  }
#pragma unroll
  for (int a = 0; a < 4; ++a) {
    int n = n0 + 8 * a;
    float* dst = agg + ((size_t)(b * 32) + n) * 512 + vg * 16;
#pragma unroll
    for (int j = 0; j < 16; ++j) atomicAdd(&dst[j], acc[a][j]);
  }
}

// ---------------- add new-token term into agg (in place) --------------------------
__global__ __launch_bounds__(256) void agg_finish(float* __restrict__ agg,
                                                  const float* __restrict__ probs,
                                                  const float* __restrict__ cKV_t) {
  const int idx = blockIdx.x * 256 + threadIdx.x;  // 65536
  const int b = idx >> 14;
  const int n = (idx >> 9) & 31;
  const int v = idx & 511;
  agg[idx] += probs[((size_t)(b * 32) + n) * T1 + TT] * cKV_t[b * 512 + v];
}

// ---------------- out1: attn_out[b][n][d] = sum_v agg[b][n][v] * W_UV[v][n][d] ----
// grid 32 (n); block 128 (d)
__global__ __launch_bounds__(128) void out1_kernel(const float* __restrict__ agg,
                                                   const float* __restrict__ W_UV,
                                                   float* __restrict__ attn_out) {
  const int n = blockIdx.x;
  const int d = threadIdx.x;
  float acc[4] = {0.f, 0.f, 0.f, 0.f};
  for (int v = 0; v < 512; ++v) {
    float w = W_UV[(size_t)v * 4096 + n * 128 + d];
#pragma unroll
    for (int b = 0; b < 4; ++b) acc[b] += agg[((size_t)(b * 32) + n) * 512 + v] * w;
  }
#pragma unroll
  for (int b = 0; b < 4; ++b) attn_out[(size_t)b * 4096 + n * 128 + d] = acc[b];
}

// ---------------- finalize: f32 output + cache tails ------------------------------
__global__ __launch_bounds__(256) void finalize_kernel(const float* __restrict__ outf,
                                                       const float* __restrict__ cKV_t,
                                                       const float* __restrict__ kR_t,
                                                       float* __restrict__ out) {
  int idx = blockIdx.x * 256 + threadIdx.x;  // 26624 total
  if (idx < 16384) {
    out[idx] = outf[idx];
    return;
  }
  idx -= 16384;
  if (idx < 2048) {
    int b = idx >> 9, v = idx & 511;
    out[16384 + ((size_t)b * T1 + TT) * 512 + v] = cKV_t[idx];
    return;
  }
  idx -= 2048;
  if (idx < 8192) {
    int b = idx >> 11;
    int c = idx & 2047;
    out[16384 + (size_t)8390656 + ((size_t)b * T1 + TT) * 2048 + c] = kR_t[idx];
  }
}

// ---------------- launcher --------------------------------------------------------
extern "C" void kernel_launch(void* const* d_in, const int* in_sizes, int n_in,
                              void* d_out, int out_size, void* d_ws, size_t ws_size,
                              hipStream_t stream) {
  (void)in_sizes; (void)n_in; (void)out_size; (void)ws_size;
  const float* hidden = (const float*)d_in[0];
  const float* mask   = (const float*)d_in[1];
  const float* cKV    = (const float*)d_in[2];
  const float* kR     = (const float*)d_in[3];
  const float* W_DQ   = (const float*)d_in[4];
  const float* W_DKV  = (const float*)d_in[5];
  const float* W_UQ_C = (const float*)d_in[6];
  const float* W_UQ_R = (const float*)d_in[7];
  const float* W_UK_C = (const float*)d_in[8];
  const float* W_UV_C = (const float*)d_in[9];
  const float* W_KR   = (const float*)d_in[10];
  const float* W_O    = (const float*)d_in[11];

  float* ws = (float*)d_ws;
  // ws layout (float offsets) — total 729,216 floats = 2.92 MB
  const size_t WS_CQ = 0;           // 6144
  const size_t WS_CKVT = 6144;      // 2048
  const size_t WS_KRT = 8192;       // 8192
  const size_t WS_QC = 16384;       // 16384
  const size_t WS_QR = 32768;       // 8192
  const size_t WS_OUTF = 40960;     // 16384
  const size_t WS_AGG = 57344;      // 65536  (zeroed region ends at 122880)
  const size_t WS_ATTN = 122880;    // 16384  (fully written by out1)
  const size_t WS_QABS = 139264;    // 65536  (fully written by absorb)
  const size_t WS_SCORES = 204800;  // 524416 (fully written by scores+softmax)

  float* out0 = (float*)d_out;
  float* out_ckv = out0 + 16384;
  float* out_kr = out_ckv + (size_t)8390656;

  hipMemsetAsync(d_ws, 0, 122880 * sizeof(float), stream);

  // projections from hidden
  gemv_atomic<<<dim3(48, 2), 256, 0, stream>>>(hidden, W_DQ, ws + WS_CQ, 1536, 4096, 2048);
  gemv_atomic<<<dim3(16, 2), 256, 0, stream>>>(hidden, W_DKV, ws + WS_CKVT, 512, 4096, 2048);
  gemv_atomic<<<dim3(64, 2), 256, 0, stream>>>(hidden, W_KR, ws + WS_KRT, 2048, 4096, 2048);
  // q projections from cQ
  gemv_atomic<<<dim3(128, 2), 256, 0, stream>>>(ws + WS_CQ, W_UQ_C, ws + WS_QC, 4096, 1536, 768);
  gemv_atomic<<<dim3(64, 2), 256, 0, stream>>>(ws + WS_CQ, W_UQ_R, ws + WS_QR, 2048, 1536, 768);
  // absorb W_UK into q
  absorb_kernel<<<dim3(32, 4), 128, 0, stream>>>(ws + WS_QC, W_UK_C, ws + WS_QABS);
  // cache concat-copies (f32 -> f32)
  copy_cache<<<8192, 256, 0, stream>>>(cKV, out_ckv, 19, (size_t)T1 * 512);
  copy_cache<<<8192, 256, 0, stream>>>(kR, out_kr, 21, (size_t)T1 * 2048);
  // prefix scores
  scores_kernel<<<dim3(256, 4), 256, 0, stream>>>(cKV, kR, ws + WS_QABS, ws + WS_QR,
                                                  ws + WS_SCORES);
  // softmax
  softmax_kernel<<<128, 256, 0, stream>>>(ws + WS_SCORES, mask, ws + WS_QABS,
                                          ws + WS_CKVT, ws + WS_QR, ws + WS_KRT);
  // p @ cKV aggregation (absorbed V)
  agg_kernel<<<dim3(32, 4), 256, 0, stream>>>(cKV, ws + WS_SCORES, ws + WS_AGG);
  agg_finish<<<256, 256, 0, stream>>>(ws + WS_AGG, ws + WS_SCORES, ws + WS_CKVT);
  // apply W_UV then W_O
  out1_kernel<<<32, 128, 0, stream>>>(ws + WS_AGG, W_UV_C, ws + WS_ATTN);
  gemv_atomic<<<dim3(128, 2), 256, 0, stream>>>(ws + WS_ATTN, W_O, ws + WS_OUTF, 4096, 4096, 2048);
  // f32 output + cache tails
  finalize_kernel<<<104, 256, 0, stream>>>(ws + WS_OUTF, ws + WS_CKVT, ws + WS_KRT, out0);
}

// Round 5
// 295.711 us; speedup vs baseline: 2.1067x; 2.1067x over previous
//
#include <hip/hip_runtime.h>

#define TT 4096
#define T1 4097

using f32x4 = __attribute__((ext_vector_type(4))) float;

// ---------------- batched GEMV: Y[b][j] += sum_k X[b][k] * W[k][j], all f32 --------
// block 256: ct = tid&7 (4 cols -> 32 cols/block), kt = tid>>3 (32-way k parallel)
// grid (N/32, KS); chunk = K/KS. Y pre-zeroed, atomically accumulated.
__global__ __launch_bounds__(256) void gemv_atomic(const float* __restrict__ X,
                                                   const float* __restrict__ W,
                                                   float* __restrict__ Y,
                                                   int N, int K, int chunk) {
  const int tid = threadIdx.x;
  const int ct = tid & 7;
  const int kt = tid >> 3;
  const int col0 = blockIdx.x * 32 + ct * 4;
  const int k0 = blockIdx.y * chunk;
  float acc[4][4];
#pragma unroll
  for (int c = 0; c < 4; ++c)
#pragma unroll
    for (int b = 0; b < 4; ++b) acc[c][b] = 0.f;
  const int iters = chunk >> 5;
  for (int i = 0; i < iters; ++i) {
    int k = k0 + kt + (i << 5);
    f32x4 w4 = *(const f32x4*)(W + (size_t)k * N + col0);
    float xb[4];
#pragma unroll
    for (int b = 0; b < 4; ++b) xb[b] = X[(size_t)b * K + k];
#pragma unroll
    for (int c = 0; c < 4; ++c)
#pragma unroll
      for (int b = 0; b < 4; ++b) acc[c][b] += w4[c] * xb[b];
  }
  __shared__ float red[256][16];
#pragma unroll
  for (int c = 0; c < 4; ++c)
#pragma unroll
    for (int b = 0; b < 4; ++b) red[tid][c * 4 + b] = acc[c][b];
  __syncthreads();
  for (int s = 16; s >= 1; s >>= 1) {
    if (kt < s) {
#pragma unroll
      for (int j = 0; j < 16; ++j) red[tid][j] += red[tid + 8 * s][j];
    }
    __syncthreads();
  }
  if (kt == 0) {
#pragma unroll
    for (int c = 0; c < 4; ++c)
#pragma unroll
      for (int b = 0; b < 4; ++b)
        atomicAdd(&Y[(size_t)b * N + col0 + c], red[ct][c * 4 + b]);
  }
}

// ---------------- absorb: q_abs[b][n][v] = sum_d qC[b][n][d] * W_UK[v][n][d] ------
// grid (32 n, 4 vt); block 128: one thread per v
__global__ __launch_bounds__(128) void absorb_kernel(const float* __restrict__ qC,
                                                     const float* __restrict__ W_UK,
                                                     float* __restrict__ q_abs) {
  const int n = blockIdx.x, vt = blockIdx.y;
  __shared__ float qs[4][128];
  for (int i = threadIdx.x; i < 512; i += 128)
    qs[i >> 7][i & 127] = qC[(size_t)(i >> 7) * 4096 + n * 128 + (i & 127)];
  __syncthreads();
  const int v = vt * 128 + threadIdx.x;
  const float* wp = W_UK + (size_t)v * 4096 + n * 128;
  float acc[4] = {0.f, 0.f, 0.f, 0.f};
#pragma unroll 4
  for (int c = 0; c < 32; ++c) {
    f32x4 w4 = *(const f32x4*)(wp + c * 4);
#pragma unroll
    for (int j = 0; j < 4; ++j)
#pragma unroll
      for (int b = 0; b < 4; ++b) acc[b] += qs[b][c * 4 + j] * w4[j];
  }
#pragma unroll
  for (int b = 0; b < 4; ++b) q_abs[((size_t)(b * 32) + n) * 512 + v] = acc[b];
}

// ---------------- fused prefix scores + cache concat-copy (all f32) ---------------
// grid (256 t-tiles of 16, 4 b); block 256: n = tid&31, tg = tid>>5 (2 t each)
__global__ __launch_bounds__(256) void scores_copy(const float* __restrict__ cKV,
                                                   const float* __restrict__ kR,
                                                   const float* __restrict__ q_abs,
                                                   const float* __restrict__ qR,
                                                   float* __restrict__ scores,
                                                   float* __restrict__ out_ckv,
                                                   float* __restrict__ out_kr) {
  const int b = blockIdx.y;
  const int t0 = blockIdx.x * 16;
  const int tid = threadIdx.x;
  __shared__ float ck[16][512];  // 32 KB
  // cKV tile: global -> LDS + pass-through copy to new cache
  for (int i = tid; i < 2048; i += 256) {
    int tl = i >> 7, vc = i & 127;
    f32x4 v = *(const f32x4*)(cKV + ((size_t)b * TT + t0 + tl) * 512 + vc * 4);
    *(f32x4*)&ck[tl][vc * 4] = v;
    *(f32x4*)(out_ckv + ((size_t)b * T1 + t0 + tl) * 512 + vc * 4) = v;
  }
  // kR tile: pass-through copy (strided score-read below hits L2)
  for (int i = tid; i < 8192; i += 256) {
    int tl = i >> 9, c = i & 511;
    f32x4 v = *(const f32x4*)(kR + ((size_t)b * TT + t0 + tl) * 2048 + c * 4);
    *(f32x4*)(out_kr + ((size_t)b * T1 + t0 + tl) * 2048 + c * 4) = v;
  }
  __syncthreads();
  const int n = tid & 31, tg = tid >> 5;
  const float* qa = q_abs + ((size_t)(b * 32) + n) * 512;
  float acc[2] = {0.f, 0.f};
#pragma unroll 4
  for (int vc = 0; vc < 128; ++vc) {
    f32x4 q4 = *(const f32x4*)(qa + vc * 4);
#pragma unroll
    for (int i = 0; i < 2; ++i) {
      f32x4 c4 = *(const f32x4*)&ck[tg * 2 + i][vc * 4];
#pragma unroll
      for (int j = 0; j < 4; ++j) acc[i] += q4[j] * c4[j];
    }
  }
  const float* qrp = qR + (size_t)b * 2048 + n * 64;
#pragma unroll 4
  for (int rc = 0; rc < 16; ++rc) {
    f32x4 q4 = *(const f32x4*)(qrp + rc * 4);
#pragma unroll
    for (int i = 0; i < 2; ++i) {
      f32x4 k4 = *(const f32x4*)(kR + (((size_t)b * TT + t0 + tg * 2 + i) * 32 + n) * 64 + rc * 4);
#pragma unroll
      for (int j = 0; j < 4; ++j) acc[i] += q4[j] * k4[j];
    }
  }
#pragma unroll
  for (int i = 0; i < 2; ++i)
    scores[((size_t)(b * 32) + n) * T1 + t0 + tg * 2 + i] = acc[i];
}

// ---------------- softmax (adds new-token score, mask, scale) ---------------------
// grid 128 (b*32+n); block 256
__global__ __launch_bounds__(256) void softmax_kernel(float* __restrict__ scores,
                                                      const float* __restrict__ mask,
                                                      const float* __restrict__ q_abs,
                                                      const float* __restrict__ cKV_t,
                                                      const float* __restrict__ qR,
                                                      const float* __restrict__ kR_t) {
  const int b = blockIdx.x >> 5, n = blockIdx.x & 31;
  const int tid = threadIdx.x;
  float* srow = scores + ((size_t)(b * 32) + n) * T1;
  const float* qa = q_abs + ((size_t)(b * 32) + n) * 512;
  const float* ck = cKV_t + b * 512;
  float p = qa[tid] * ck[tid] + qa[tid + 256] * ck[tid + 256];
  if (tid < 64) p += qR[(size_t)b * 2048 + n * 64 + tid] * kR_t[(size_t)b * 2048 + n * 64 + tid];
  __shared__ float lds[256];
  lds[tid] = p;
  __syncthreads();
  for (int s = 128; s >= 1; s >>= 1) {
    if (tid < s) lds[tid] += lds[tid + s];
    __syncthreads();
  }
  const float sT = lds[0];
  __syncthreads();
  const float inv_scale = 0.0721687836487032f;  // 1/sqrt(192)
  const float* mrow = mask + ((size_t)(b * 32) + n) * T1;
  float lmax = -1e30f;
  for (int t = tid; t < T1; t += 256) {
    float s0 = (t < TT) ? srow[t] : sT;
    float val = s0 * inv_scale + mrow[t] * (-1e9f);
    srow[t] = val;
    lmax = fmaxf(lmax, val);
  }
  lds[tid] = lmax;
  __syncthreads();
  for (int s = 128; s >= 1; s >>= 1) {
    if (tid < s) lds[tid] = fmaxf(lds[tid], lds[tid + s]);
    __syncthreads();
  }
  const float M = lds[0];
  __syncthreads();
  float lsum = 0.f;
  for (int t = tid; t < T1; t += 256) {
    float e = expf(srow[t] - M);
    srow[t] = e;
    lsum += e;
  }
  lds[tid] = lsum;
  __syncthreads();
  for (int s = 128; s >= 1; s >>= 1) {
    if (tid < s) lds[tid] += lds[tid + s];
    __syncthreads();
  }
  const float inv = 1.0f / lds[0];
  for (int t = tid; t < T1; t += 256) srow[t] *= inv;
}

// ---------------- aggregation partials: aggP[b][chunk][n][v] ----------------------
// grid (NC, 4 b, 2 vh); block 256: vg = tid&31 (8 v), ng = tid>>5 (4 n)
// tlen = 4096/NC (<=256), tshift = log2(tlen)
__global__ __launch_bounds__(256) void agg_part(const float* __restrict__ cKV,
                                                const float* __restrict__ probs,
                                                float* __restrict__ aggP,
                                                int tlen, int tshift, int NC) {
  const int chunk = blockIdx.x, b = blockIdx.y, vh = blockIdx.z;
  const int t0 = chunk * tlen;
  const int tid = threadIdx.x;
  const int vg = tid & 31, ng = tid >> 5;
  __shared__ float p_lds[32 * 257];
  const int cnt = tlen << 5;  // 32 * tlen
  for (int i = tid; i < cnt; i += 256) {
    int n = i >> tshift, tl = i & (tlen - 1);
    p_lds[n * 257 + tl] = probs[((size_t)(b * 32) + n) * T1 + t0 + tl];
  }
  __syncthreads();
  float acc[4][8];
#pragma unroll
  for (int a = 0; a < 4; ++a)
#pragma unroll
    for (int j = 0; j < 8; ++j) acc[a][j] = 0.f;
  const float* cbase = cKV + ((size_t)b * TT + t0) * 512 + vh * 256 + vg * 8;
  for (int t = 0; t < tlen; t += 2) {
    f32x4 c00 = *(const f32x4*)(cbase + (size_t)t * 512);
    f32x4 c01 = *(const f32x4*)(cbase + (size_t)t * 512 + 4);
    f32x4 c10 = *(const f32x4*)(cbase + (size_t)(t + 1) * 512);
    f32x4 c11 = *(const f32x4*)(cbase + (size_t)(t + 1) * 512 + 4);
#pragma unroll
    for (int a = 0; a < 4; ++a) {
      float p0 = p_lds[(ng * 4 + a) * 257 + t];
      float p1 = p_lds[(ng * 4 + a) * 257 + t + 1];
#pragma unroll
      for (int j = 0; j < 4; ++j) {
        acc[a][j] += p0 * c00[j] + p1 * c10[j];
        acc[a][j + 4] += p0 * c01[j] + p1 * c11[j];
      }
    }
  }
#pragma unroll
  for (int a = 0; a < 4; ++a) {
    int n = ng * 4 + a;
    float* dst = aggP + (((size_t)b * NC + chunk) * 32 + n) * 512 + vh * 256 + vg * 8;
#pragma unroll
    for (int q = 0; q < 2; ++q) {
      f32x4 v;
#pragma unroll
      for (int j = 0; j < 4; ++j) v[j] = acc[a][q * 4 + j];
      *(f32x4*)(dst + q * 4) = v;
    }
  }
}

// ---------------- reduce partials + new-token term -> agg -------------------------
__global__ __launch_bounds__(256) void agg_reduce(const float* __restrict__ aggP,
                                                  const float* __restrict__ probs,
                                                  const float* __restrict__ cKV_t,
                                                  float* __restrict__ agg, int NC) {
  const int idx = blockIdx.x * 256 + threadIdx.x;  // 65536
  const int b = idx >> 14;
  const int n = (idx >> 9) & 31;
  const int v = idx & 511;
  float s = probs[((size_t)(b * 32) + n) * T1 + TT] * cKV_t[b * 512 + v];
  const float* pp = aggP + (((size_t)b * NC) * 32 + n) * 512 + v;
#pragma unroll 4
  for (int c = 0; c < NC; ++c) s += pp[(size_t)c * 32 * 512];
  agg[idx] = s;
}

// ---------------- out1: attn_out[b][n][d] += sum_v agg[b][n][v] * W_UV[v][n][d] ---
// grid (32 n, 8 vc of 64 v); block 256: d = tid&127, bh = tid>>7 (b = bh, bh+2)
__global__ __launch_bounds__(256) void out1_kernel(const float* __restrict__ agg,
                                                   const float* __restrict__ W_UV,
                                                   float* __restrict__ attn_out) {
  const int n = blockIdx.x, vc = blockIdx.y;
  const int tid = threadIdx.x;
  const int d = tid & 127, bh = tid >> 7;
  const float* a0 = agg + ((size_t)(bh * 32) + n) * 512;
  const float* a1 = agg + ((size_t)((bh + 2) * 32) + n) * 512;
  float acc0 = 0.f, acc1 = 0.f;
#pragma unroll 4
  for (int vv = 0; vv < 64; ++vv) {
    int v = vc * 64 + vv;
    float w = W_UV[(size_t)v * 4096 + n * 128 + d];
    acc0 += a0[v] * w;
    acc1 += a1[v] * w;
  }
  atomicAdd(&attn_out[(size_t)bh * 4096 + n * 128 + d], acc0);
  atomicAdd(&attn_out[(size_t)(bh + 2) * 4096 + n * 128 + d], acc1);
}

// ---------------- finalize: f32 output + cache tails ------------------------------
__global__ __launch_bounds__(256) void finalize_kernel(const float* __restrict__ outf,
                                                       const float* __restrict__ cKV_t,
                                                       const float* __restrict__ kR_t,
                                                       float* __restrict__ out) {
  int idx = blockIdx.x * 256 + threadIdx.x;  // 26624 total
  if (idx < 16384) {
    out[idx] = outf[idx];
    return;
  }
  idx -= 16384;
  if (idx < 2048) {
    int b = idx >> 9, v = idx & 511;
    out[16384 + ((size_t)b * T1 + TT) * 512 + v] = cKV_t[idx];
    return;
  }
  idx -= 2048;
  if (idx < 8192) {
    int b = idx >> 11;
    int c = idx & 2047;
    out[16384 + (size_t)8390656 + ((size_t)b * T1 + TT) * 2048 + c] = kR_t[idx];
  }
}

// ---------------- launcher --------------------------------------------------------
extern "C" void kernel_launch(void* const* d_in, const int* in_sizes, int n_in,
                              void* d_out, int out_size, void* d_ws, size_t ws_size,
                              hipStream_t stream) {
  (void)in_sizes; (void)n_in; (void)out_size;
  const float* hidden = (const float*)d_in[0];
  const float* mask   = (const float*)d_in[1];
  const float* cKV    = (const float*)d_in[2];
  const float* kR     = (const float*)d_in[3];
  const float* W_DQ   = (const float*)d_in[4];
  const float* W_DKV  = (const float*)d_in[5];
  const float* W_UQ_C = (const float*)d_in[6];
  const float* W_UQ_R = (const float*)d_in[7];
  const float* W_UK_C = (const float*)d_in[8];
  const float* W_UV_C = (const float*)d_in[9];
  const float* W_KR   = (const float*)d_in[10];
  const float* W_O    = (const float*)d_in[11];

  float* ws = (float*)d_ws;
  // ws layout (float offsets)
  const size_t WS_CQ = 0;           // 6144
  const size_t WS_CKVT = 6144;      // 2048
  const size_t WS_KRT = 8192;       // 8192
  const size_t WS_QC = 16384;       // 16384
  const size_t WS_QR = 32768;       // 8192
  const size_t WS_OUTF = 40960;     // 16384 (atomic target)
  const size_t WS_ATTN = 57344;     // 16384 (atomic target) — zero region [0,73728)
  const size_t WS_AGG = 73728;      // 65536  (written by agg_reduce)
  const size_t WS_QABS = 139264;    // 65536  (written by absorb)
  const size_t WS_SCORES = 204800;  // 524416 (written by scores+softmax)
  const size_t WS_AGGP = 729216;    // NC*65536 floats of partials

  // pick chunk count by available scratch (deterministic per session)
  int NC = 8;
  if (ws_size >= (WS_AGGP + (size_t)64 * 65536) * 4) NC = 64;
  else if (ws_size >= (WS_AGGP + (size_t)32 * 65536) * 4) NC = 32;
  else if (ws_size >= (WS_AGGP + (size_t)16 * 65536) * 4) NC = 16;
  const int tlen = 4096 / NC;
  int tshift = 0;
  while ((1 << tshift) < tlen) ++tshift;

  float* out0 = (float*)d_out;
  float* out_ckv = out0 + 16384;
  float* out_kr = out_ckv + (size_t)8390656;

  hipMemsetAsync(d_ws, 0, 73728 * sizeof(float), stream);

  // projections from hidden (k-split for occupancy)
  gemv_atomic<<<dim3(48, 8), 256, 0, stream>>>(hidden, W_DQ, ws + WS_CQ, 1536, 4096, 512);
  gemv_atomic<<<dim3(16, 16), 256, 0, stream>>>(hidden, W_DKV, ws + WS_CKVT, 512, 4096, 256);
  gemv_atomic<<<dim3(64, 8), 256, 0, stream>>>(hidden, W_KR, ws + WS_KRT, 2048, 4096, 512);
  // q projections from cQ
  gemv_atomic<<<dim3(128, 4), 256, 0, stream>>>(ws + WS_CQ, W_UQ_C, ws + WS_QC, 4096, 1536, 384);
  gemv_atomic<<<dim3(64, 4), 256, 0, stream>>>(ws + WS_CQ, W_UQ_R, ws + WS_QR, 2048, 1536, 384);
  // absorb W_UK into q
  absorb_kernel<<<dim3(32, 4), 128, 0, stream>>>(ws + WS_QC, W_UK_C, ws + WS_QABS);
  // fused prefix scores + cache concat-copies
  scores_copy<<<dim3(256, 4), 256, 0, stream>>>(cKV, kR, ws + WS_QABS, ws + WS_QR,
                                                ws + WS_SCORES, out_ckv, out_kr);
  // softmax
  softmax_kernel<<<128, 256, 0, stream>>>(ws + WS_SCORES, mask, ws + WS_QABS,
                                          ws + WS_CKVT, ws + WS_QR, ws + WS_KRT);
  // p @ cKV aggregation: partials then reduce (+ new-token term)
  agg_part<<<dim3(NC, 4, 2), 256, 0, stream>>>(cKV, ws + WS_SCORES, ws + WS_AGGP,
                                               tlen, tshift, NC);
  agg_reduce<<<256, 256, 0, stream>>>(ws + WS_AGGP, ws + WS_SCORES, ws + WS_CKVT,
                                      ws + WS_AGG, NC);
  // apply W_UV then W_O
  out1_kernel<<<dim3(32, 8), 256, 0, stream>>>(ws + WS_AGG, W_UV_C, ws + WS_ATTN);
  gemv_atomic<<<dim3(128, 8), 256, 0, stream>>>(ws + WS_ATTN, W_O, ws + WS_OUTF, 4096, 4096, 512);
  // f32 output + cache tails
  finalize_kernel<<<104, 256, 0, stream>>>(ws + WS_OUTF, ws + WS_CKVT, ws + WS_KRT, out0);
}